// Round 2
// baseline (228.684 us; speedup 1.0000x reference)
//
#include <hip/hip_runtime.h>
#include <math.h>

#define N_NODES 100000
#define N_EDGES 1000000
#define IN_DIM  128
#define OUT_DIM 64
#define NEG     0.2f

#define SCAN_BLOCKS 391   // ceil(100000/256)
#define EDGE_BLOCKS 3907  // ceil(1000000/256): one edge per thread
#define GEMM_BLOCKS 782   // ceil(100000/128)
#define FUSED_BLOCKS (GEMM_BLOCKS + EDGE_BLOCKS)   // 4689

// ---------------------------------------------------------------------------
// kA (fused): two block roles in one grid.
//  - GEMM role (782 blocks, blockIdx%6==0): Wh = h@W^T + b via bf16x2 split
//    MFMA (identical math to R1's k1_mfma).
//  - HIST role (3907 blocks): rank[e] = atomicAdd(&deg8[(hid&7)*N + t], 1).
//    8-way privatized by hist-block index: 8x more cache sectors under the
//    1M device-scope RMWs (R1 counters: 31MB write-back signature, VALU 2.9%
//    -> atomic-serialization-bound). Histogram depends only on ei, so it
//    overlaps the GEMM's MFMA work instead of serializing after it.
//  Roles interleaved (every 6th block is GEMM) so both co-reside per CU.
// ---------------------------------------------------------------------------
typedef __attribute__((ext_vector_type(8))) short short8;   // 8 bf16 = 4 VGPR
typedef __attribute__((ext_vector_type(4))) float f32x4;

#define MFMA(A, B, C) __builtin_amdgcn_mfma_f32_16x16x32_bf16(A, B, C, 0, 0, 0)

union U16 { unsigned u[4]; short8 s; };

__device__ __forceinline__ void split8(const float* x, short8& hi, short8& lo) {
    U16 H, L;
#pragma unroll
    for (int i = 0; i < 4; ++i) {
        float a = x[2 * i], b = x[2 * i + 1];
        unsigned ua = __float_as_uint(a), ub = __float_as_uint(b);
        unsigned ha = ua & 0xffff0000u, hb = ub & 0xffff0000u;
        H.u[i] = (ua >> 16) | hb;
        float la = a - __uint_as_float(ha);     // exact (low mantissa bits)
        float lb = b - __uint_as_float(hb);
        L.u[i] = (__float_as_uint(la) >> 16) | (__float_as_uint(lb) & 0xffff0000u);
    }
    hi = H.s; lo = L.s;
}

__global__ __launch_bounds__(256, 4) void kA_fused(
    const float* __restrict__ h, const float* __restrict__ W,
    const float* __restrict__ Wb, const float* __restrict__ aw,
    float* __restrict__ Wh, float* __restrict__ s_src, float* __restrict__ s_tgt,
    const int* __restrict__ ei, unsigned* __restrict__ deg8,
    unsigned* __restrict__ rank)
{
    // 34816 B: staging (wfh 16K | wfl 16K) then reused as tr[128][68] f32
    __shared__ float4 smem4[2176];

    if ((blockIdx.x % 6) != 0) {
        // ---------------- HIST role ----------------
        const int hid = blockIdx.x - blockIdx.x / 6 - 1;     // 0..3906
        const int e = hid * 256 + threadIdx.x;
        if (e < N_EDGES) {
            int t = ei[N_EDGES + e];
            rank[e] = atomicAdd(&deg8[(size_t)(hid & 7) * N_NODES + t], 1u);
        }
        return;
    }

    // ---------------- GEMM role ----------------
    unsigned short* wfh = (unsigned short*)smem4;
    unsigned short* wfl = wfh + 8192;

    const int tid  = threadIdx.x;
    const int lane = tid & 63, w = tid >> 6;
    const int c = lane & 15, g = lane >> 4;
    const int n0 = (blockIdx.x / 6) * 128;

    // stage W as bf16 hi/lo in frag order: unit U = (nb*4+ks)*64 + lane
#pragma unroll
    for (int it = 0; it < 4; ++it) {
        int U = tid + 256 * it;                 // 0..1023
        int pos = U >> 6, l = U & 63;
        int nb = pos >> 2, ks = pos & 3;
        int r  = 16 * nb + (l & 15);
        int k0 = 32 * ks + 8 * (l >> 4);
        float a[8];
        *(float4*)&a[0] = *(const float4*)(W + r * IN_DIM + k0);
        *(float4*)&a[4] = *(const float4*)(W + r * IN_DIM + k0 + 4);
        short8 hi, lo; split8(a, hi, lo);
        *(short8*)(wfh + (size_t)U * 8) = hi;   // stride-1 b128 writes
        *(short8*)(wfl + (size_t)U * 8) = lo;
    }
    __syncthreads();

    const int na0 = n0 + 32 * w + c;
    const float* hp0 = h + (size_t)min(na0, N_NODES - 1) * IN_DIM + 8 * g;
    const float* hp1 = h + (size_t)min(na0 + 16, N_NODES - 1) * IN_DIM + 8 * g;

    f32x4 acc[2][4];
    {
        f32x4 z = {0.f, 0.f, 0.f, 0.f};
#pragma unroll
        for (int m = 0; m < 2; ++m)
#pragma unroll
            for (int nb = 0; nb < 4; ++nb) acc[m][nb] = z;
    }

#pragma unroll 2
    for (int ks = 0; ks < 4; ++ks) {
        short8 bh[4], bl[4];
#pragma unroll
        for (int nb = 0; nb < 4; ++nb) {
            int u = ((nb * 4 + ks) * 64 + lane) * 8;
            bh[nb] = *(const short8*)(wfh + u);
            bl[nb] = *(const short8*)(wfl + u);
        }
        float am[8];
        short8 ah, al;
        *(float4*)&am[0] = *(const float4*)(hp0 + 32 * ks);
        *(float4*)&am[4] = *(const float4*)(hp0 + 32 * ks + 4);
        split8(am, ah, al);
#pragma unroll
        for (int nb = 0; nb < 4; ++nb) {
            acc[0][nb] = MFMA(ah, bh[nb], acc[0][nb]);
            acc[0][nb] = MFMA(ah, bl[nb], acc[0][nb]);
            acc[0][nb] = MFMA(al, bh[nb], acc[0][nb]);
        }
        *(float4*)&am[0] = *(const float4*)(hp1 + 32 * ks);
        *(float4*)&am[4] = *(const float4*)(hp1 + 32 * ks + 4);
        split8(am, ah, al);
#pragma unroll
        for (int nb = 0; nb < 4; ++nb) {
            acc[1][nb] = MFMA(ah, bh[nb], acc[1][nb]);
            acc[1][nb] = MFMA(ah, bl[nb], acc[1][nb]);
            acc[1][nb] = MFMA(al, bh[nb], acc[1][nb]);
        }
    }

    // epilogue: bias + score dot-products.
    // D-frag: lane holds Wh[32w + 16m + 4g + r][16nb + c], r = 0..3.
    float wb[4], w1[4], w2[4];
#pragma unroll
    for (int nb = 0; nb < 4; ++nb) {
        wb[nb] = Wb[16 * nb + c];
        w1[nb] = aw[16 * nb + c];
        w2[nb] = aw[OUT_DIM + 16 * nb + c];
    }
#pragma unroll
    for (int m = 0; m < 2; ++m)
#pragma unroll
        for (int r = 0; r < 4; ++r) {
            float s1 = 0.f, s2 = 0.f;
#pragma unroll
            for (int nb = 0; nb < 4; ++nb) {
                float v = acc[m][nb][r] + wb[nb];
                acc[m][nb][r] = v;
                s1 = fmaf(v, w1[nb], s1);
                s2 = fmaf(v, w2[nb], s2);
            }
#pragma unroll
            for (int mk = 1; mk < 16; mk <<= 1) {
                s1 += __shfl_xor(s1, mk);
                s2 += __shfl_xor(s2, mk);
            }
            if (c == 0) {
                int node = n0 + 32 * w + 16 * m + 4 * g + r;
                if (node < N_NODES) { s_src[node] = s1; s_tgt[node] = s2; }
            }
        }

    __syncthreads();                 // all LDS W reads done; reuse as tr
    float* tr = (float*)smem4;       // tr[128][68]
#pragma unroll
    for (int m = 0; m < 2; ++m)
#pragma unroll
        for (int nb = 0; nb < 4; ++nb)
#pragma unroll
            for (int r = 0; r < 4; ++r)
                tr[(32 * w + 16 * m + 4 * g + r) * 68 + 16 * nb + c] = acc[m][nb][r];
    __syncthreads();

    // coalesced Wh store: 2048 float4, 8/thread
#pragma unroll
    for (int j = 0; j < 8; ++j) {
        int idx = tid + 256 * j;              // 0..2047
        int nloc = idx >> 4, d4 = idx & 15;
        int node = n0 + nloc;
        if (node < N_NODES)
            ((float4*)Wh)[(size_t)node * 16 + d4] =
                *(const float4*)&tr[nloc * 68 + d4 * 4];
    }
}

// ---------------------------------------------------------------------------
// k_mid: streaming pass over edges: ex = exp(leaky(score)), block sums ->
// bsum. Blocks < SCAN_BLOCKS additionally compute psum[b] = sum of node
// degrees for the scan (absorbs old k_scan1 -> one fewer dispatch).
// No atomics anywhere -> pure BW, ~5 us.
// ---------------------------------------------------------------------------
__global__ __launch_bounds__(256) void k_mid(
    const int* __restrict__ ei, const float* __restrict__ s_src,
    const float* __restrict__ s_tgt, const float* __restrict__ ab,
    const unsigned* __restrict__ deg8,
    float* __restrict__ exv, float* __restrict__ bsum,
    unsigned* __restrict__ psum)
{
    const float ab0 = ab[0];
    float lsum = 0.f;
    const int e = blockIdx.x * 256 + threadIdx.x;
    if (e < N_EDGES) {
        int s = ei[e], t = ei[N_EDGES + e];
        float x = s_src[s] + s_tgt[t] + ab0;
        float l = x > 0.f ? x : NEG * x;
        float ex = __expf(l);
        exv[e] = ex;
        lsum = ex;
    }
#pragma unroll
    for (int off = 32; off; off >>= 1) lsum += __shfl_xor(lsum, off);
    __shared__ float ssum[4];
    if ((threadIdx.x & 63) == 0) ssum[threadIdx.x >> 6] = lsum;
    __syncthreads();
    if (threadIdx.x == 0)
        bsum[blockIdx.x] = ssum[0] + ssum[1] + ssum[2] + ssum[3];

    if (blockIdx.x < SCAN_BLOCKS) {
        const int i = blockIdx.x * 256 + threadIdx.x;
        unsigned v = 0;
        if (i < N_NODES) {
#pragma unroll
            for (int x = 0; x < 8; ++x) v += deg8[(size_t)x * N_NODES + i];
        }
#pragma unroll
        for (int off = 32; off; off >>= 1) v += __shfl_xor(v, off);
        __shared__ unsigned us[4];
        if ((threadIdx.x & 63) == 0) us[threadIdx.x >> 6] = v;
        __syncthreads();
        if (threadIdx.x == 0)
            psum[blockIdx.x] = us[0] + us[1] + us[2] + us[3];
    }
}

// ---------------------------------------------------------------------------
// k_scan2: exclusive scan of psum -> poff; reduce bsum -> gsum (unchanged).
// ---------------------------------------------------------------------------
__global__ __launch_bounds__(512) void k_scan2(
    const unsigned* __restrict__ psum, unsigned* __restrict__ poff,
    const float* __restrict__ bsum, float* __restrict__ gsum)
{
    __shared__ unsigned sc[512];
    __shared__ float    sf[8];
    const int t = threadIdx.x;

    unsigned v = (t < SCAN_BLOCKS) ? psum[t] : 0u;
    sc[t] = v;
    __syncthreads();
    for (int off = 1; off < 512; off <<= 1) {
        unsigned u = (t >= off) ? sc[t - off] : 0u;
        __syncthreads();
        sc[t] += u;
        __syncthreads();
    }
    if (t < SCAN_BLOCKS) poff[t] = sc[t] - v;   // exclusive

    float s = 0.f;
    for (int i = t; i < EDGE_BLOCKS; i += 512) s += bsum[i];
#pragma unroll
    for (int off = 32; off; off >>= 1) s += __shfl_xor(s, off);
    if ((t & 63) == 0) sf[t >> 6] = s;
    __syncthreads();
    if (t == 0) {
        float tot = 0.f;
#pragma unroll
        for (int i = 0; i < 8; ++i) tot += sf[i];
        gsum[0] = tot;
    }
}

// ---------------------------------------------------------------------------
// k_scan3: row[] (CSR) + per-copy bases row8[x][t] = row[t] + sum_{x'<x}
// deg8[x'][t]. k3 then resolves pos = row8[copy][t] + local rank.
// ---------------------------------------------------------------------------
__global__ __launch_bounds__(256) void k_scan3(
    const unsigned* __restrict__ deg8, const unsigned* __restrict__ poff,
    unsigned* __restrict__ row, unsigned* __restrict__ row8)
{
    __shared__ unsigned sc[256];
    const int t = threadIdx.x;
    const int i = blockIdx.x * 256 + t;
    unsigned d[8];
    unsigned tot = 0;
    if (i < N_NODES) {
#pragma unroll
        for (int x = 0; x < 8; ++x) {
            d[x] = deg8[(size_t)x * N_NODES + i];
            tot += d[x];
        }
    }
    sc[t] = tot;
    __syncthreads();
    for (int off = 1; off < 256; off <<= 1) {
        unsigned u = (t >= off) ? sc[t - off] : 0u;
        __syncthreads();
        sc[t] += u;
        __syncthreads();
    }
    if (i < N_NODES) {
        unsigned base = poff[blockIdx.x] + sc[t] - tot;   // exclusive
        row[i] = base;
        unsigned run = base;
#pragma unroll
        for (int x = 0; x < 8; ++x) {
            row8[(size_t)x * N_NODES + i] = run;
            run += d[x];
        }
    }
    if (i == 0) row[N_NODES] = N_EDGES;
}

// ---------------------------------------------------------------------------
// K3: bin fill, NO atomics: pos = row8[copy(e)][t] + rank[e];
// copy(e) = (e>>8)&7 (the hist block that processed e).
// ---------------------------------------------------------------------------
__global__ __launch_bounds__(256) void k3_fill(
    const int* __restrict__ ei, const float* __restrict__ exv,
    const unsigned* __restrict__ rank, const unsigned* __restrict__ row8,
    int2* __restrict__ bin)
{
    const int e = blockIdx.x * blockDim.x + threadIdx.x;
    if (e >= N_EDGES) return;
    int t = ei[N_EDGES + e];
    int c = (e >> 8) & 7;
    unsigned pos = row8[(size_t)c * N_NODES + t] + rank[e];
    bin[pos] = make_int2(ei[e], __float_as_int(exv[e]));
}

// ---------------------------------------------------------------------------
// K4: gather — wave per tgt node, lane = dim (unchanged from R1).
// ---------------------------------------------------------------------------
__global__ __launch_bounds__(256) void k_gather(
    const unsigned* __restrict__ row, const int2* __restrict__ bin,
    const float* __restrict__ gsum, const float* __restrict__ Wh,
    float* __restrict__ out)
{
    const int lane = threadIdx.x & 63;
    const int t = blockIdx.x * 4 + (threadIdx.x >> 6);
    if (t >= N_NODES) return;
    const unsigned beg = row[t], end = row[t + 1];
    float a0 = 0.f, a1 = 0.f, a2 = 0.f, a3 = 0.f;
    for (unsigned base = beg; base < end; base += 64) {
        const int cnt = (int)min(64u, end - base);
        int2 p = make_int2(0, 0);
        if (lane < cnt) p = bin[base + lane];      // coalesced 8B/lane
        int j = 0;
        for (; j + 4 <= cnt; j += 4) {
            int   s0 = __shfl(p.x, j);     float w0 = __int_as_float(__shfl(p.y, j));
            int   s1 = __shfl(p.x, j + 1); float w1 = __int_as_float(__shfl(p.y, j + 1));
            int   s2 = __shfl(p.x, j + 2); float w2 = __int_as_float(__shfl(p.y, j + 2));
            int   s3 = __shfl(p.x, j + 3); float w3 = __int_as_float(__shfl(p.y, j + 3));
            float v0 = Wh[(size_t)s0 * OUT_DIM + lane];
            float v1 = Wh[(size_t)s1 * OUT_DIM + lane];
            float v2 = Wh[(size_t)s2 * OUT_DIM + lane];
            float v3 = Wh[(size_t)s3 * OUT_DIM + lane];
            a0 = fmaf(w0, v0, a0);
            a1 = fmaf(w1, v1, a1);
            a2 = fmaf(w2, v2, a2);
            a3 = fmaf(w3, v3, a3);
        }
        for (; j < cnt; ++j) {
            int   s = __shfl(p.x, j);
            float w = __int_as_float(__shfl(p.y, j));
            a0 = fmaf(w, Wh[(size_t)s * OUT_DIM + lane], a0);
        }
    }
    float v = ((a0 + a1) + (a2 + a3)) * (1.0f / gsum[0]);
    out[(size_t)t * OUT_DIM + lane] = v > 0.f ? v : NEG * v;
}

extern "C" void kernel_launch(void* const* d_in, const int* in_sizes, int n_in,
                              void* d_out, int out_size, void* d_ws, size_t ws_size,
                              hipStream_t stream)
{
    const float* h  = (const float*)d_in[0];
    const float* W  = (const float*)d_in[1];
    const float* Wb = (const float*)d_in[2];
    const float* aw = (const float*)d_in[3];
    const float* ab = (const float*)d_in[4];
    const int*   ei = (const int*)d_in[5];

    // ws layout: Wh[N*64] f32 | s_src[N] | s_tgt[N] | deg8[8N] u32 |
    //            row[N+1] u32 | row8[8N] u32 | psum[512] | poff[512] |
    //            bin[E] int2 | exv[E] f32 | rank[E] u32 | bsum[4096] | gsum
    float* ws      = (float*)d_ws;
    float* Wh      = ws;
    float* s_src   = Wh + (size_t)N_NODES * OUT_DIM;
    float* s_tgt   = s_src + N_NODES;
    unsigned* deg8   = (unsigned*)(s_tgt + N_NODES);
    unsigned* row    = deg8 + (size_t)8 * N_NODES;
    unsigned* row8   = row + N_NODES + 1;
    unsigned* psum   = row8 + (size_t)8 * N_NODES;
    unsigned* poff   = psum + 512;
    int2*     bin    = (int2*)(poff + 512);
    float*    exv    = (float*)(bin + N_EDGES);
    unsigned* rank   = (unsigned*)(exv + N_EDGES);
    float*    bsum   = (float*)(rank + N_EDGES);
    float*    gsum   = bsum + 4096;

    float* out = (float*)d_out;

    hipMemsetAsync((void*)deg8, 0, (size_t)8 * N_NODES * sizeof(unsigned), stream);

    kA_fused<<<FUSED_BLOCKS, 256, 0, stream>>>(h, W, Wb, aw, Wh, s_src, s_tgt,
                                               ei, deg8, rank);
    k_mid<<<EDGE_BLOCKS, 256, 0, stream>>>(ei, s_src, s_tgt, ab, deg8,
                                           exv, bsum, psum);
    k_scan2<<<1, 512, 0, stream>>>(psum, poff, bsum, gsum);
    k_scan3<<<SCAN_BLOCKS, 256, 0, stream>>>(deg8, poff, row, row8);
    k3_fill<<<EDGE_BLOCKS, 256, 0, stream>>>(ei, exv, rank, row8, bin);
    k_gather<<<(N_NODES + 3) / 4, 256, 0, stream>>>(row, bin, gsum, Wh, out);
}